// Round 2
// baseline (742.415 us; speedup 1.0000x reference)
//
#include <hip/hip_runtime.h>
#include <math.h>

#define DIMX 256
#define NFEAT 32
#define BATCH 512
#define HEADS 8
#define DHEAD 32
#define KNN 17
#define QKV_W 768
#define SCALE_F 0.17677669529663687f

// ---------------- Stage A: reprs = mean(x,axis=1) @ W_repr + b_repr; normalize ----------------
__global__ void repr_kernel(const float* __restrict__ x, const float* __restrict__ W_repr,
                            const float* __restrict__ b_repr, float* __restrict__ normed) {
  int b = blockIdx.x, t = threadIdx.x;
  __shared__ float mean_s[DIMX];
  __shared__ float red[DIMX];
  float s = 0.f;
#pragma unroll
  for (int n = 0; n < NFEAT; ++n) s += x[(size_t)(b*NFEAT+n)*DIMX + t];
  mean_s[t] = s * (1.0f/NFEAT);
  __syncthreads();
  float acc = b_repr[t];
  for (int d = 0; d < DIMX; ++d) acc += mean_s[d] * W_repr[d*DIMX + t];
  red[t] = acc*acc;
  __syncthreads();
  for (int off = 128; off > 0; off >>= 1) {
    if (t < off) red[t] += red[t+off];
    __syncthreads();
  }
  normed[b*DIMX + t] = acc / sqrtf(red[0]);
}

// ---------------- Stage B: sim row + top-17 (iterative argmax, ties -> lower index) ----------------
__global__ void simtopk_kernel(const float* __restrict__ normed, int* __restrict__ knn) {
  int i = blockIdx.x, t = threadIdx.x;
  __shared__ float myrow[DIMX];
  __shared__ float sims[BATCH];
  __shared__ float rv[256];
  __shared__ int   ri[256];
  myrow[t] = normed[i*DIMX + t];
  __syncthreads();
#pragma unroll
  for (int jj = 0; jj < 2; ++jj) {
    int j = t + jj*256;
    const float* row = &normed[(size_t)j*DIMX];
    float s = 0.f;
    for (int d = 0; d < DIMX; ++d) s += myrow[d] * row[d];
    sims[j] = s;  // TEMPERATURE = 1
  }
  __syncthreads();
  for (int it = 0; it < KNN; ++it) {
    float v1 = sims[t], v2 = sims[t+256];
    float mv; int mi;
    if (v2 > v1) { mv = v2; mi = t+256; } else { mv = v1; mi = t; }
    rv[t] = mv; ri[t] = mi;
    __syncthreads();
    for (int off = 128; off > 0; off >>= 1) {
      if (t < off) {
        if (rv[t+off] > rv[t] || (rv[t+off] == rv[t] && ri[t+off] < ri[t])) {
          rv[t] = rv[t+off]; ri[t] = ri[t+off];
        }
      }
      __syncthreads();
    }
    if (t == 0) { knn[i*32 + it] = ri[0]; sims[ri[0]] = -INFINITY; }
    __syncthreads();
  }
}

// ---------------- Stage C: qkv = x @ W_qkv  (M=16384, K=256, N=768) ----------------
#define BM 128
#define BN 64
#define BK 16
__global__ void qkv_gemm(const float* __restrict__ A, const float* __restrict__ B,
                         float* __restrict__ C) {
  __shared__ float As[BK][BM];   // transposed tile
  __shared__ float Bs[BK][BN];
  int t = threadIdx.x;
  int tx = t & 15, ty = t >> 4;
  int row0 = blockIdx.x * BM;
  int col0 = blockIdx.y * BN;
  int ar = t >> 1, ac = (t & 1) * 8;
  int br = t >> 4, bc = (t & 15) * 4;
  float acc[8][4] = {};
  for (int k0 = 0; k0 < 256; k0 += BK) {
    float4 a0 = *(const float4*)&A[(size_t)(row0+ar)*256 + k0 + ac];
    float4 a1 = *(const float4*)&A[(size_t)(row0+ar)*256 + k0 + ac + 4];
    As[ac+0][ar] = a0.x; As[ac+1][ar] = a0.y; As[ac+2][ar] = a0.z; As[ac+3][ar] = a0.w;
    As[ac+4][ar] = a1.x; As[ac+5][ar] = a1.y; As[ac+6][ar] = a1.z; As[ac+7][ar] = a1.w;
    *(float4*)&Bs[br][bc] = *(const float4*)&B[(size_t)(k0+br)*QKV_W + col0 + bc];
    __syncthreads();
#pragma unroll
    for (int kk = 0; kk < BK; ++kk) {
      float4 av0 = *(float4*)&As[kk][ty*8];
      float4 av1 = *(float4*)&As[kk][ty*8+4];
      float4 bv  = *(float4*)&Bs[kk][tx*4];
      float a[8] = {av0.x,av0.y,av0.z,av0.w,av1.x,av1.y,av1.z,av1.w};
      float bb[4] = {bv.x,bv.y,bv.z,bv.w};
#pragma unroll
      for (int i = 0; i < 8; ++i)
#pragma unroll
        for (int j = 0; j < 4; ++j) acc[i][j] += a[i]*bb[j];
    }
    __syncthreads();
  }
#pragma unroll
  for (int i = 0; i < 8; ++i) {
    float4 o = {acc[i][0], acc[i][1], acc[i][2], acc[i][3]};
    *(float4*)&C[(size_t)(row0+ty*8+i)*QKV_W + col0 + tx*4] = o;
  }
}

// ---------------- Stage D: thread-per-(feature,head) attention + fused out-projection ----------------
// Block = one sample (256 threads = 32 features x 8 heads).
// Each thread: local 17-neighbor softmax (no barriers), 32 PV accumulators in regs.
__global__ __launch_bounds__(256, 2) void attn_kernel(
    const float* __restrict__ qkv, const int* __restrict__ knn,
    const float* __restrict__ W_out, const float* __restrict__ b_out,
    float* __restrict__ out) {
  int b = blockIdx.x, t = threadIdx.x;
  int n = t >> 3, h = t & 7;
  __shared__ float out_rows[NFEAT][DIMX + 1];  // +1 pad: write-phase 8-way max, read-phase multi-bank broadcast
  __shared__ int idxs[KNN];
  if (t < KNN) idxs[t] = knn[b*32 + t];
  __syncthreads();

  // q segment for this (n,h): 32 consecutive floats
  const float4* qp = (const float4*)&qkv[(size_t)(b*NFEAT + n)*QKV_W + h*DHEAD];
  float4 q[8];
#pragma unroll
  for (int i = 0; i < 8; ++i) q[i] = qp[i];

  // scores over 17 neighbors (independent gather streams)
  float sc[KNN];
#pragma unroll
  for (int j = 0; j < KNN; ++j) {
    const float4* kp = (const float4*)&qkv[(size_t)(idxs[j]*NFEAT + n)*QKV_W + 256 + h*DHEAD];
    float s = 0.f;
#pragma unroll
    for (int i = 0; i < 8; ++i) {
      float4 kv = kp[i];
      s += q[i].x*kv.x + q[i].y*kv.y + q[i].z*kv.z + q[i].w*kv.w;
    }
    sc[j] = s * SCALE_F;
  }

  // thread-local softmax
  float m = sc[0];
#pragma unroll
  for (int j = 1; j < KNN; ++j) m = fmaxf(m, sc[j]);
  float sum = 0.f;
#pragma unroll
  for (int j = 0; j < KNN; ++j) { sc[j] = __expf(sc[j] - m); sum += sc[j]; }
  float inv = 1.0f / sum;

  // PV: 32 accumulators in regs
  float acc[DHEAD] = {};
#pragma unroll
  for (int j = 0; j < KNN; ++j) {
    float p = sc[j] * inv;
    const float4* vp = (const float4*)&qkv[(size_t)(idxs[j]*NFEAT + n)*QKV_W + 512 + h*DHEAD];
#pragma unroll
    for (int i = 0; i < 8; ++i) {
      float4 vv = vp[i];
      acc[4*i+0] += p*vv.x; acc[4*i+1] += p*vv.y; acc[4*i+2] += p*vv.z; acc[4*i+3] += p*vv.w;
    }
  }
#pragma unroll
  for (int i = 0; i < DHEAD; ++i) out_rows[n][h*DHEAD + i] = acc[i];
  __syncthreads();

  // fused out-projection: thread (n,h) computes out[b, n, h*32 .. h*32+31]
  // reads only its own LDS row (multi-bank broadcast), W_out from L1.
  float acc2[DHEAD];
  const float4* bp = (const float4*)&b_out[h*DHEAD];
#pragma unroll
  for (int i = 0; i < 8; ++i) {
    float4 bo = bp[i];
    acc2[4*i+0] = bo.x; acc2[4*i+1] = bo.y; acc2[4*i+2] = bo.z; acc2[4*i+3] = bo.w;
  }
#pragma unroll 4
  for (int d = 0; d < DIMX; ++d) {
    float a = out_rows[n][d];
    const float4* wrow = (const float4*)&W_out[(size_t)d*DIMX + h*DHEAD];
#pragma unroll
    for (int i = 0; i < 8; ++i) {
      float4 w = wrow[i];
      acc2[4*i+0] += a*w.x; acc2[4*i+1] += a*w.y; acc2[4*i+2] += a*w.z; acc2[4*i+3] += a*w.w;
    }
  }
  float4* op = (float4*)&out[(size_t)(b*NFEAT + n)*DIMX + h*DHEAD];
#pragma unroll
  for (int i = 0; i < 8; ++i) {
    op[i] = make_float4(acc2[4*i+0], acc2[4*i+1], acc2[4*i+2], acc2[4*i+3]);
  }
}

extern "C" void kernel_launch(void* const* d_in, const int* in_sizes, int n_in,
                              void* d_out, int out_size, void* d_ws, size_t ws_size,
                              hipStream_t stream) {
  const float* x      = (const float*)d_in[0];
  const float* W_qkv  = (const float*)d_in[1];
  const float* W_out  = (const float*)d_in[2];
  const float* b_out  = (const float*)d_in[3];
  const float* W_repr = (const float*)d_in[4];
  const float* b_repr = (const float*)d_in[5];
  float* out = (float*)d_out;

  float* qkv    = (float*)d_ws;                          // 16384*768 f32 = 50.3 MB
  float* normed = qkv + (size_t)16384*QKV_W;             // 512*256 f32
  int*   knn    = (int*)(normed + (size_t)BATCH*DIMX);   // 512*32 int

  repr_kernel<<<BATCH, 256, 0, stream>>>(x, W_repr, b_repr, normed);
  simtopk_kernel<<<BATCH, 256, 0, stream>>>(normed, knn);
  qkv_gemm<<<dim3(16384/BM, QKV_W/BN), 256, 0, stream>>>(x, W_qkv, qkv);
  attn_kernel<<<BATCH, 256, 0, stream>>>(qkv, knn, W_out, b_out, out);
}

// Round 4
// 248.176 us; speedup vs baseline: 2.9915x; 2.9915x over previous
//
#include <hip/hip_runtime.h>
#include <math.h>

#define DIMX 256
#define NFEAT 32
#define BATCH 512
#define HEADS 8
#define DHEAD 32
#define KNN 17
#define QKV_W 768
#define SCALE_F 0.17677669529663687f

typedef unsigned int uint;
typedef unsigned short ushort_t;

__device__ inline float bf_lo(uint u) { return __uint_as_float(u << 16); }
__device__ inline float bf_hi(uint u) { return __uint_as_float(u & 0xffff0000u); }
__device__ inline ushort_t f2bf(float f) {
  uint u = __float_as_uint(f);
  return (ushort_t)((u + 0x7fffu + ((u >> 16) & 1u)) >> 16);
}
struct ushort4_t { ushort_t x, y, z, w; };

// ---------------- Stage A: reprs = mean(x,axis=1) @ W_repr + b_repr; normalize ----------------
__global__ void repr_kernel(const float* __restrict__ x, const float* __restrict__ W_repr,
                            const float* __restrict__ b_repr, float* __restrict__ normed) {
  int b = blockIdx.x, t = threadIdx.x;
  __shared__ float mean_s[DIMX];
  __shared__ float red[DIMX];
  float s = 0.f;
#pragma unroll
  for (int n = 0; n < NFEAT; ++n) s += x[(size_t)(b*NFEAT+n)*DIMX + t];
  mean_s[t] = s * (1.0f/NFEAT);
  __syncthreads();
  float acc = b_repr[t];
  for (int d = 0; d < DIMX; ++d) acc += mean_s[d] * W_repr[d*DIMX + t];
  red[t] = acc*acc;
  __syncthreads();
  for (int off = 128; off > 0; off >>= 1) {
    if (t < off) red[t] += red[t+off];
    __syncthreads();
  }
  normed[b*DIMX + t] = acc / sqrtf(red[0]);
}

// ---------------- Stage B: sim row + top-17 (iterative argmax, ties -> lower index) ----------------
__global__ void simtopk_kernel(const float* __restrict__ normed, int* __restrict__ knn) {
  int i = blockIdx.x, t = threadIdx.x;
  __shared__ float myrow[DIMX];
  __shared__ float sims[BATCH];
  __shared__ float rv[256];
  __shared__ int   ri[256];
  myrow[t] = normed[i*DIMX + t];
  __syncthreads();
#pragma unroll
  for (int jj = 0; jj < 2; ++jj) {
    int j = t + jj*256;
    const float* row = &normed[(size_t)j*DIMX];
    float s = 0.f;
    for (int d = 0; d < DIMX; ++d) s += myrow[d] * row[d];
    sims[j] = s;  // TEMPERATURE = 1
  }
  __syncthreads();
  for (int it = 0; it < KNN; ++it) {
    float v1 = sims[t], v2 = sims[t+256];
    float mv; int mi;
    if (v2 > v1) { mv = v2; mi = t+256; } else { mv = v1; mi = t; }
    rv[t] = mv; ri[t] = mi;
    __syncthreads();
    for (int off = 128; off > 0; off >>= 1) {
      if (t < off) {
        if (rv[t+off] > rv[t] || (rv[t+off] == rv[t] && ri[t+off] < ri[t])) {
          rv[t] = rv[t+off]; ri[t] = ri[t+off];
        }
      }
      __syncthreads();
    }
    if (t == 0) { knn[i*32 + it] = ri[0]; sims[ri[0]] = -INFINITY; }
    __syncthreads();
  }
}

// ---------------- Stage C: qkv = x @ W_qkv (f32 compute, bf16 store) ----------------
#define BM 128
#define BN 64
#define BK 16
__global__ void qkv_gemm(const float* __restrict__ A, const float* __restrict__ B,
                         ushort_t* __restrict__ C) {
  __shared__ float As[BK][BM];   // transposed tile
  __shared__ float Bs[BK][BN];
  int t = threadIdx.x;
  int tx = t & 15, ty = t >> 4;
  int row0 = blockIdx.x * BM;
  int col0 = blockIdx.y * BN;
  int ar = t >> 1, ac = (t & 1) * 8;
  int br = t >> 4, bc = (t & 15) * 4;
  float acc[8][4] = {};
  for (int k0 = 0; k0 < 256; k0 += BK) {
    float4 a0 = *(const float4*)&A[(size_t)(row0+ar)*256 + k0 + ac];
    float4 a1 = *(const float4*)&A[(size_t)(row0+ar)*256 + k0 + ac + 4];
    As[ac+0][ar] = a0.x; As[ac+1][ar] = a0.y; As[ac+2][ar] = a0.z; As[ac+3][ar] = a0.w;
    As[ac+4][ar] = a1.x; As[ac+5][ar] = a1.y; As[ac+6][ar] = a1.z; As[ac+7][ar] = a1.w;
    *(float4*)&Bs[br][bc] = *(const float4*)&B[(size_t)(k0+br)*QKV_W + col0 + bc];
    __syncthreads();
#pragma unroll
    for (int kk = 0; kk < BK; ++kk) {
      float4 av0 = *(float4*)&As[kk][ty*8];
      float4 av1 = *(float4*)&As[kk][ty*8+4];
      float4 bv  = *(float4*)&Bs[kk][tx*4];
      float a[8] = {av0.x,av0.y,av0.z,av0.w,av1.x,av1.y,av1.z,av1.w};
      float bb[4] = {bv.x,bv.y,bv.z,bv.w};
#pragma unroll
      for (int i = 0; i < 8; ++i)
#pragma unroll
        for (int j = 0; j < 4; ++j) acc[i][j] += a[i]*bb[j];
    }
    __syncthreads();
  }
#pragma unroll
  for (int i = 0; i < 8; ++i) {
    ushort4_t o = { f2bf(acc[i][0]), f2bf(acc[i][1]), f2bf(acc[i][2]), f2bf(acc[i][3]) };
    *(ushort4_t*)&C[(size_t)(row0+ty*8+i)*QKV_W + col0 + tx*4] = o;
  }
}

// ---------------- Stage D: attention (bf16) + fused out-projection ----------------
// Grid (BATCH, 4): block = (sample, group of 8 features), 256 threads.
// Per feature: threads 0..135 compute scores (16B/lane K loads) while threads
// 136..255 stage the 17 V rows into LDS (16B/lane) -> barrier -> all 256
// threads do PV from LDS (redundant per-thread softmax from LDS broadcast).
#define NF_BLK 8
__global__ __launch_bounds__(256, 4) void attn_kernel(
    const ushort_t* __restrict__ qkv, const int* __restrict__ knn,
    const float* __restrict__ W_out, const float* __restrict__ b_out,
    float* __restrict__ out) {
  int b = blockIdx.x, g = blockIdx.y, t = threadIdx.x;
  int n0 = g * NF_BLK;
  __shared__ float sc_s[KNN][HEADS];
  __shared__ uint  v_lds[KNN][DIMX/2];       // 17 x 128 words (256 bf16) = 8.5 KB
  __shared__ float out_rows[NF_BLK][DIMX + 1];
  __shared__ int idxs[KNN];
  if (t < KNN) idxs[t] = knn[b*32 + t];
  __syncthreads();

  for (int nn = 0; nn < NF_BLK; ++nn) {
    int n = n0 + nn;
    if (t < KNN*HEADS) {
      // scores: thread (j,h), 4x uint4 = 64B of q and k
      int j = t >> 3, h = t & 7;
      const uint4* qp = (const uint4*)&qkv[(size_t)(b*NFEAT + n)*QKV_W + h*DHEAD];
      const uint4* kp = (const uint4*)&qkv[(size_t)(idxs[j]*NFEAT + n)*QKV_W + 256 + h*DHEAD];
      float s = 0.f;
#pragma unroll
      for (int i = 0; i < 4; ++i) {
        uint4 qv = qp[i], kv = kp[i];
        s += bf_lo(qv.x)*bf_lo(kv.x) + bf_hi(qv.x)*bf_hi(kv.x)
           + bf_lo(qv.y)*bf_lo(kv.y) + bf_hi(qv.y)*bf_hi(kv.y)
           + bf_lo(qv.z)*bf_lo(kv.z) + bf_hi(qv.z)*bf_hi(kv.z)
           + bf_lo(qv.w)*bf_lo(kv.w) + bf_hi(qv.w)*bf_hi(kv.w);
      }
      sc_s[j][h] = s * SCALE_F;
    } else {
      // stage V rows: 17 rows x 512 B = 544 uint4 loads over 120 threads
      for (int idx = t - 136; idx < KNN*32; idx += 120) {
        int row = idx >> 5, col = idx & 31;
        uint4 w = ((const uint4*)&qkv[(size_t)(idxs[row]*NFEAT + n)*QKV_W + 512])[col];
        ((uint4*)&v_lds[row][0])[col] = w;
      }
    }
    __syncthreads();
    // PV: thread t owns output dim t; softmax recomputed per-thread (LDS broadcast)
    {
      int h = t >> 5;
      float e[KNN];
      float m = -INFINITY;
#pragma unroll
      for (int j = 0; j < KNN; ++j) { e[j] = sc_s[j][h]; m = fmaxf(m, e[j]); }
      float sum = 0.f;
#pragma unroll
      for (int j = 0; j < KNN; ++j) { e[j] = __expf(e[j] - m); sum += e[j]; }
      float inv = 1.0f / sum;
      int word = t >> 1;
      bool hi = (t & 1);
      float acc = 0.f;
#pragma unroll
      for (int j = 0; j < KNN; ++j) {
        uint w = v_lds[j][word];
        float v = hi ? bf_hi(w) : bf_lo(w);
        acc += e[j] * v;
      }
      out_rows[nn][t] = acc * inv;
    }
    __syncthreads();
  }

  // fused out-projection: thread t owns output column t for the block's 8 rows
  float acc2[NF_BLK];
  float bo = b_out[t];
#pragma unroll
  for (int r = 0; r < NF_BLK; ++r) acc2[r] = bo;
  for (int d = 0; d < DIMX; ++d) {
    float w = W_out[(size_t)d*DIMX + t];
#pragma unroll
    for (int r = 0; r < NF_BLK; ++r) acc2[r] += out_rows[r][d] * w;
  }
#pragma unroll
  for (int r = 0; r < NF_BLK; ++r) out[(size_t)(b*NFEAT + n0 + r)*DIMX + t] = acc2[r];
}

extern "C" void kernel_launch(void* const* d_in, const int* in_sizes, int n_in,
                              void* d_out, int out_size, void* d_ws, size_t ws_size,
                              hipStream_t stream) {
  const float* x      = (const float*)d_in[0];
  const float* W_qkv  = (const float*)d_in[1];
  const float* W_out  = (const float*)d_in[2];
  const float* b_out  = (const float*)d_in[3];
  const float* W_repr = (const float*)d_in[4];
  const float* b_repr = (const float*)d_in[5];
  float* out = (float*)d_out;

  ushort_t* qkv  = (ushort_t*)d_ws;                       // 16384*768 bf16 = 25.2 MB
  float* normed  = (float*)(qkv + (size_t)16384*QKV_W);   // 512*256 f32
  int*   knn     = (int*)(normed + (size_t)BATCH*DIMX);   // 512*32 int

  repr_kernel<<<BATCH, 256, 0, stream>>>(x, W_repr, b_repr, normed);
  simtopk_kernel<<<BATCH, 256, 0, stream>>>(normed, knn);
  qkv_gemm<<<dim3(16384/BM, QKV_W/BN), 256, 0, stream>>>(x, W_qkv, qkv);
  attn_kernel<<<dim3(BATCH, NFEAT/NF_BLK), 256, 0, stream>>>(qkv, knn, W_out, b_out, out);
}

// Round 5
// 137.778 us; speedup vs baseline: 5.3885x; 1.8013x over previous
//
#include <hip/hip_runtime.h>
#include <math.h>

#define DIMX 256
#define NFEAT 32
#define BATCH 512
#define HEADS 8
#define DHEAD 32
#define KNN 17
#define QKV_W 768
#define SCALE_F 0.17677669529663687f

typedef unsigned int uint;
typedef unsigned short ushort_t;
typedef __attribute__((ext_vector_type(8))) short short8_t;   // 8 bf16 (4 VGPRs)
typedef __attribute__((ext_vector_type(4))) float float4_t;   // MFMA acc

__device__ inline float bf_lo(uint u) { return __uint_as_float(u << 16); }
__device__ inline float bf_hi(uint u) { return __uint_as_float(u & 0xffff0000u); }
__device__ inline ushort_t f2bf(float f) {
  uint u = __float_as_uint(f);
  return (ushort_t)((u + 0x7fffu + ((u >> 16) & 1u)) >> 16);
}

// ---------------- Stage A: reprs = mean(x,axis=1) @ W_repr + b_repr; normalize ----------------
__global__ void repr_kernel(const float* __restrict__ x, const float* __restrict__ W_repr,
                            const float* __restrict__ b_repr, float* __restrict__ normed) {
  int b = blockIdx.x, t = threadIdx.x;
  __shared__ float mean_s[DIMX];
  __shared__ float red[DIMX];
  float s = 0.f;
#pragma unroll
  for (int n = 0; n < NFEAT; ++n) s += x[(size_t)(b*NFEAT+n)*DIMX + t];
  mean_s[t] = s * (1.0f/NFEAT);
  __syncthreads();
  float acc = b_repr[t];
  for (int d = 0; d < DIMX; ++d) acc += mean_s[d] * W_repr[d*DIMX + t];
  red[t] = acc*acc;
  __syncthreads();
  for (int off = 128; off > 0; off >>= 1) {
    if (t < off) red[t] += red[t+off];
    __syncthreads();
  }
  normed[b*DIMX + t] = acc / sqrtf(red[0]);
}

// ---------------- Stage B: sim row + top-17 (wave-shuffle argmax, ties -> lower index) ----------
__global__ void simtopk_kernel(const float* __restrict__ normed, int* __restrict__ knn) {
  int i = blockIdx.x, t = threadIdx.x;
  __shared__ float myrow[DIMX];
  __shared__ float sims[BATCH];
  __shared__ float rv[4];
  __shared__ int   ri[4];
  myrow[t] = normed[i*DIMX + t];
  __syncthreads();
#pragma unroll
  for (int jj = 0; jj < 2; ++jj) {
    int j = t + jj*256;
    const float* row = &normed[(size_t)j*DIMX];
    float s = 0.f;
    for (int d = 0; d < DIMX; ++d) s += myrow[d] * row[d];
    sims[j] = s;  // TEMPERATURE = 1
  }
  __syncthreads();
  for (int it = 0; it < KNN; ++it) {
    float v1 = sims[t], v2 = sims[t+256];
    float mv; int mi;
    if (v2 > v1) { mv = v2; mi = t+256; } else { mv = v1; mi = t; }
#pragma unroll
    for (int off = 32; off > 0; off >>= 1) {
      float ov = __shfl_down(mv, off);
      int   oi = __shfl_down(mi, off);
      if (ov > mv || (ov == mv && oi < mi)) { mv = ov; mi = oi; }
    }
    if ((t & 63) == 0) { rv[t >> 6] = mv; ri[t >> 6] = mi; }
    __syncthreads();
    if (t == 0) {
      float bv = rv[0]; int bi = ri[0];
#pragma unroll
      for (int wv = 1; wv < 4; ++wv)
        if (rv[wv] > bv || (rv[wv] == bv && ri[wv] < bi)) { bv = rv[wv]; bi = ri[wv]; }
      knn[i*32 + it] = bi;
      sims[bi] = -INFINITY;
    }
    __syncthreads();
  }
}

// ---------------- prep: cast x->bf16; transpose-cast W_qkv, W_out to [N][K] bf16 ---------------
__global__ void prep_kernel(const float* __restrict__ x, const float* __restrict__ Wq,
                            const float* __restrict__ Wo, ushort_t* __restrict__ xbf,
                            ushort_t* __restrict__ wqT, ushort_t* __restrict__ woT) {
  int bid = blockIdx.x, t = threadIdx.x;
  if (bid < 2048) {                       // x: 16384*256 = 4.19M elems, 8 per thread
    size_t base = ((size_t)bid*256 + t)*8;
    float4 f0 = *(const float4*)&x[base];
    float4 f1 = *(const float4*)&x[base+4];
    uint4 o;
    o.x = (uint)f2bf(f0.x) | ((uint)f2bf(f0.y) << 16);
    o.y = (uint)f2bf(f0.z) | ((uint)f2bf(f0.w) << 16);
    o.z = (uint)f2bf(f1.x) | ((uint)f2bf(f1.y) << 16);
    o.w = (uint)f2bf(f1.z) | ((uint)f2bf(f1.w) << 16);
    *(uint4*)&xbf[base] = o;
  } else if (bid < 2048 + QKV_W) {        // W_qkv [256][768] -> wqT [768][256]
    int c = bid - 2048;
    wqT[(size_t)c*DIMX + t] = f2bf(Wq[(size_t)t*QKV_W + c]);
  } else {                                // W_out [256][256] -> woT [256][256]
    int c = bid - 2048 - QKV_W;
    woT[(size_t)c*DIMX + t] = f2bf(Wo[(size_t)t*DIMX + c]);
  }
}

// ---------------- MFMA bf16 GEMM: C[M,N] = A[M,K] @ Bt[N,K]^T (+bias), 128x64 tile ------------
// 4 waves: wave (wr,wc) owns 64x32; frags 4(m) x 2(n) of 16x16; BK=64 (2 k-subs of 32).
// Layouts (m89-verified family): A-frag lane l: row=l&15, k=(l>>4)*8+[0..7]; B-frag: col=l&15,
// same k; C/D: col=l&15, row=(l>>4)*4+reg.
template<bool OUTF32>
__global__ __launch_bounds__(256, 2) void mfma_gemm(
    const ushort_t* __restrict__ A, const ushort_t* __restrict__ Bt,
    void* __restrict__ Cout, const float* __restrict__ bias, int M, int N, int K) {
  __shared__ ushort_t As[128][72];  // +8 pad: 144B rows -> 2-way (free) LDS access
  __shared__ ushort_t Bs[64][72];
  int t = threadIdx.x;
  int l = t & 63, w = t >> 6;
  int wr = w >> 1, wc = w & 1;
  int row0 = blockIdx.x * 128, col0 = blockIdx.y * 64;
  float4_t acc[4][2] = {};
  for (int k0 = 0; k0 < K; k0 += 64) {
#pragma unroll
    for (int i = 0; i < 4; ++i) {       // A tile: 128x64 bf16 = 1024 16B-chunks
      int c = t + 256*i;
      int ar = c >> 3, ac8 = (c & 7) * 8;
      *(uint4*)&As[ar][ac8] = *(const uint4*)&A[(size_t)(row0+ar)*K + k0 + ac8];
    }
#pragma unroll
    for (int i = 0; i < 2; ++i) {       // Bt tile: 64x64 = 512 chunks
      int c = t + 256*i;
      int br = c >> 3, bc8 = (c & 7) * 8;
      *(uint4*)&Bs[br][bc8] = *(const uint4*)&Bt[(size_t)(col0+br)*K + k0 + bc8];
    }
    __syncthreads();
#pragma unroll
    for (int ks = 0; ks < 2; ++ks) {
      int kk = ks*32 + (l >> 4)*8;
      short8_t a[4], b[2];
#pragma unroll
      for (int m = 0; m < 4; ++m) a[m] = *(short8_t*)&As[wr*64 + m*16 + (l & 15)][kk];
#pragma unroll
      for (int n = 0; n < 2; ++n) b[n] = *(short8_t*)&Bs[wc*32 + n*16 + (l & 15)][kk];
#pragma unroll
      for (int m = 0; m < 4; ++m)
#pragma unroll
        for (int n = 0; n < 2; ++n)
          acc[m][n] = __builtin_amdgcn_mfma_f32_16x16x32_bf16(a[m], b[n], acc[m][n], 0, 0, 0);
    }
    __syncthreads();
  }
  int crow = (l >> 4) * 4, ccol = l & 15;
#pragma unroll
  for (int m = 0; m < 4; ++m)
#pragma unroll
    for (int n = 0; n < 2; ++n) {
      int col = col0 + wc*32 + n*16 + ccol;
#pragma unroll
      for (int r = 0; r < 4; ++r) {
        int row = row0 + wr*64 + m*16 + crow + r;
        if (OUTF32) ((float*)Cout)[(size_t)row*N + col] = acc[m][n][r] + bias[col];
        else        ((ushort_t*)Cout)[(size_t)row*N + col] = f2bf(acc[m][n][r]);
      }
    }
}

// ---------------- Stage D: attention (bf16 gather) -> attn_out bf16 ---------------------------
#define NF_BLK 8
__global__ __launch_bounds__(256, 4) void attn_kernel(
    const ushort_t* __restrict__ qkv, const int* __restrict__ knn,
    ushort_t* __restrict__ attn_out) {
  int b = blockIdx.x, g = blockIdx.y, t = threadIdx.x;
  int n0 = g * NF_BLK;
  __shared__ float sc_s[KNN][HEADS];
  __shared__ uint  v_lds[KNN][DIMX/2];       // 8.5 KB
  __shared__ int idxs[KNN];
  if (t < KNN) idxs[t] = knn[b*32 + t];
  __syncthreads();

  for (int nn = 0; nn < NF_BLK; ++nn) {
    int n = n0 + nn;
    if (t < KNN*HEADS) {
      int j = t >> 3, h = t & 7;
      const uint4* qp = (const uint4*)&qkv[(size_t)(b*NFEAT + n)*QKV_W + h*DHEAD];
      const uint4* kp = (const uint4*)&qkv[(size_t)(idxs[j]*NFEAT + n)*QKV_W + 256 + h*DHEAD];
      float s = 0.f;
#pragma unroll
      for (int i = 0; i < 4; ++i) {
        uint4 qv = qp[i], kv = kp[i];
        s += bf_lo(qv.x)*bf_lo(kv.x) + bf_hi(qv.x)*bf_hi(kv.x)
           + bf_lo(qv.y)*bf_lo(kv.y) + bf_hi(qv.y)*bf_hi(kv.y)
           + bf_lo(qv.z)*bf_lo(kv.z) + bf_hi(qv.z)*bf_hi(kv.z)
           + bf_lo(qv.w)*bf_lo(kv.w) + bf_hi(qv.w)*bf_hi(kv.w);
      }
      sc_s[j][h] = s * SCALE_F;
    } else {
      for (int idx = t - 136; idx < KNN*32; idx += 120) {
        int row = idx >> 5, col = idx & 31;
        uint4 wv = ((const uint4*)&qkv[(size_t)(idxs[row]*NFEAT + n)*QKV_W + 512])[col];
        ((uint4*)&v_lds[row][0])[col] = wv;
      }
    }
    __syncthreads();
    if (t < HEADS) {        // normalize once per head
      float m = -INFINITY;
#pragma unroll
      for (int j = 0; j < KNN; ++j) m = fmaxf(m, sc_s[j][t]);
      float sum = 0.f;
      float e[KNN];
#pragma unroll
      for (int j = 0; j < KNN; ++j) { e[j] = __expf(sc_s[j][t] - m); sum += e[j]; }
      float inv = 1.0f / sum;
#pragma unroll
      for (int j = 0; j < KNN; ++j) sc_s[j][t] = e[j] * inv;
    }
    __syncthreads();
    {   // PV: thread t owns output dim t
      int h = t >> 5;
      int word = t >> 1;
      bool hi = (t & 1);
      float acc = 0.f;
#pragma unroll
      for (int j = 0; j < KNN; ++j) {
        uint wv = v_lds[j][word];
        float v = hi ? bf_hi(wv) : bf_lo(wv);
        acc += sc_s[j][h] * v;
      }
      attn_out[(size_t)(b*NFEAT + n)*DIMX + t] = f2bf(acc);
    }
    __syncthreads();
  }
}

extern "C" void kernel_launch(void* const* d_in, const int* in_sizes, int n_in,
                              void* d_out, int out_size, void* d_ws, size_t ws_size,
                              hipStream_t stream) {
  const float* x      = (const float*)d_in[0];
  const float* W_qkv  = (const float*)d_in[1];
  const float* W_out  = (const float*)d_in[2];
  const float* b_out  = (const float*)d_in[3];
  const float* W_repr = (const float*)d_in[4];
  const float* b_repr = (const float*)d_in[5];
  float* out = (float*)d_out;

  ushort_t* qkv      = (ushort_t*)d_ws;                        // 16384*768 bf16
  ushort_t* xbf      = qkv + (size_t)16384*QKV_W;              // 16384*256
  ushort_t* wqT      = xbf + (size_t)16384*DIMX;               // 768*256
  ushort_t* woT      = wqT + (size_t)QKV_W*DIMX;               // 256*256
  ushort_t* attn_out = woT + (size_t)DIMX*DIMX;                // 16384*256
  float*    normed   = (float*)(attn_out + (size_t)16384*DIMX);
  int*      knn      = (int*)(normed + (size_t)BATCH*DIMX);

  repr_kernel<<<BATCH, 256, 0, stream>>>(x, W_repr, b_repr, normed);
  simtopk_kernel<<<BATCH, 256, 0, stream>>>(normed, knn);
  prep_kernel<<<2048 + QKV_W + DIMX, 256, 0, stream>>>(x, W_qkv, W_out, xbf, wqT, woT);
  mfma_gemm<false><<<dim3(16384/128, QKV_W/64), 256, 0, stream>>>(
      xbf, wqT, qkv, nullptr, 16384, QKV_W, DIMX);
  attn_kernel<<<dim3(BATCH, NFEAT/NF_BLK), 256, 0, stream>>>(qkv, knn, attn_out);
  mfma_gemm<true><<<dim3(16384/128, DIMX/64), 256, 0, stream>>>(
      attn_out, woT, out, b_out, 16384, DIMX, DIMX);
}